// Round 19
// baseline (123.572 us; speedup 1.0000x reference)
//
#include <hip/hip_runtime.h>
#include <hip/hip_bf16.h>
#include <stdint.h>
#include <float.h>

#define B_ 2
#define N_ 8192
#define C_ 64
#define K_ 16
#define D_IN 131     // 2C+3
#define XS_STRIDE 168
#define QPB 16       // queries per block (8 waves x 2 queries, 512 threads)
#define QPW 2        // queries per wave
#define CAP 128      // survivor buffer capacity per query

typedef __attribute__((ext_vector_type(8))) short short8v;
typedef __attribute__((ext_vector_type(4))) float f32x4;
typedef unsigned long long ull;

// sentinel: larger than any real key, but FINITE as f64 (NaN would break fmin/fmax)
#define SENT_U64 0x7F7FFFFFFFFFFFFFull

__device__ __forceinline__ float sq3(float x, float y, float z) {
#pragma clang fp contract(off)
  return (x * x + y * y) + z * z;
}

__device__ __forceinline__ uint64_t shfl_xor_u64(uint64_t x, int mask) {
  int lo = __shfl_xor((int)(uint32_t)(x & 0xffffffffull), mask, 64);
  int hi = __shfl_xor((int)(uint32_t)(x >> 32), mask, 64);
  return ((uint64_t)(uint32_t)hi << 32) | (uint32_t)lo;
}

__device__ __forceinline__ double shfl_xor_f64(double x, int mask) {
  return __builtin_bit_cast(double, shfl_xor_u64(__builtin_bit_cast(uint64_t, x), mask));
}

__device__ __forceinline__ uint64_t pack_key_u64(float d, int idx) {
  return ((uint64_t)__float_as_uint(d) << 32) | (uint32_t)idx;
}

// branchless sorted-insert: precondition key < hd[15]; 15-stage min/max ladder.
__device__ __forceinline__ void insert16(double* hd, double key) {
  hd[15] = key;
#pragma unroll
  for (int z = 15; z >= 1; --z) {
    double a = hd[z - 1], b = hd[z];
    hd[z - 1] = fmin(a, b);
    hd[z] = fmax(a, b);
  }
}

// exact reference distance (bit-identical to all passing rounds)
__device__ __forceinline__ float exact_d(float qx, float qy, float qz, float xxq,
                                         float4 cd) {
  float dot2 = fmaf(qz, cd.z, fmaf(qy, cd.y, qx * cd.x));
  float dtmp;
  {
#pragma clang fp contract(off)
    dtmp = (xxq + cd.w) - dot2;
  }
  return fmaxf(dtmp, 0.0f);
}

// ---- merged prep: W -> bf16 fragments, coords -> c4 = (2cx,2cy,2cz,|c|^2) ----
__global__ __launch_bounds__(256) void prep(const float* __restrict__ coords,
                                            const float* __restrict__ W,
                                            __hip_bfloat16* __restrict__ wfrag,
                                            float4* __restrict__ c4) {
  int i = blockIdx.x * 256 + threadIdx.x;
  if (i < 4 * 5 * 64 * 8) {
    int j = i & 7;
    int l = (i >> 3) & 63;
    int ks = (i >> 9) % 5;
    int nt = (i >> 9) / 5;
    int k = ks * 32 + (l >> 4) * 8 + j;
    int col = nt * 16 + (l & 15);
    float v = (k < D_IN) ? W[k * 64 + col] : 0.0f;
    wfrag[i] = __float2bfloat16(v);
  }
  int j2 = i - 4 * 5 * 64 * 8;
  if (j2 >= 0 && j2 < B_ * N_) {
    float cx = coords[j2 * 3 + 0], cy = coords[j2 * 3 + 1], cz = coords[j2 * 3 + 2];
    c4[j2] = make_float4(2.0f * cx, 2.0f * cy, 2.0f * cz, sq3(cx, cy, cz));
  }
}

// ------------- KNN: global-direct, 512 threads (8 waves x 2 queries) -------------
__global__ __launch_bounds__(512) void knn_kernel(const float* __restrict__ coords,
                                                  const float4* __restrict__ c4,
                                                  int* __restrict__ idxout) {
  __shared__ ull sbuf[QPB][CAP];
  __shared__ int scnt[QPB];
  const int t = threadIdx.x;
  const int w = t >> 6;                // wave 0..7
  const int lane = t & 63;
  const int blk = blockIdx.x;          // 1024 blocks: 512 per batch
  const int bb = blk >> 9;
  const int qbase = (blk & 511) * QPB;
  const float* cb = coords + (size_t)bb * N_ * 3;
  const float4* cg = c4 + (size_t)bb * N_;

  // this wave's 2 queries in registers (raw coords)
  float qx[QPW], qy[QPW], qz[QPW], xxq[QPW];
#pragma unroll
  for (int r = 0; r < QPW; ++r) {
    int n = qbase + w * QPW + r;
    qx[r] = cb[n * 3 + 0]; qy[r] = cb[n * 3 + 1]; qz[r] = cb[n * 3 + 2];
    xxq[r] = sq3(qx[r], qy[r], qz[r]);
  }
  if (t < QPB) scnt[t] = 0;
  __syncthreads();  // scnt visible before scan-2 pushes

// proxy = q.(2c) - w : 3 fma (the -w rides the innermost fma operand-negation)
#define PROXY(r, cd) fmaf(qz[r], (cd).z, fmaf(qy[r], (cd).y, fmaf(qx[r], (cd).x, -(cd).w)))

  // ---- scan 1 (global-direct, 4-deep ILP): per-lane running MAX proxy ----
  float M[QPW];
#pragma unroll
  for (int r = 0; r < QPW; ++r) M[r] = -FLT_MAX;

  for (int j0 = 0; j0 < N_; j0 += 256) {
    float4 ca = cg[j0 + lane];
    float4 cb2 = cg[j0 + 64 + lane];
    float4 cc = cg[j0 + 128 + lane];
    float4 cd = cg[j0 + 192 + lane];
#pragma unroll
    for (int r = 0; r < QPW; ++r) {
      float p0 = PROXY(r, ca);
      float p1 = PROXY(r, cb2);
      float p2 = PROXY(r, cc);
      float p3 = PROXY(r, cd);
      M[r] = fmaxf(M[r], fmaxf(fmaxf(p0, p1), fmaxf(p2, p3)));
    }
  }

  // ---- threshold: 16th LARGEST of the 64 lane-maxima per query ----
  float A[QPW], pT[QPW];
#pragma unroll
  for (int r = 0; r < QPW; ++r) { A[r] = M[r]; pT[r] = -FLT_MAX; }
#pragma unroll
  for (int rd = 0; rd < 16; ++rd) {
#pragma unroll
    for (int r = 0; r < QPW; ++r) {
      float g = A[r];
      g = fmaxf(g, __shfl_xor(g, 1, 64));
      g = fmaxf(g, __shfl_xor(g, 2, 64));
      g = fmaxf(g, __shfl_xor(g, 4, 64));
      g = fmaxf(g, __shfl_xor(g, 8, 64));
      g = fmaxf(g, __shfl_xor(g, 16, 64));
      g = fmaxf(g, __shfl_xor(g, 32, 64));
      pT[r] = g;
      A[r] = (A[r] == g) ? -FLT_MAX : A[r];
    }
  }
  // conservative proxy threshold X (few-ulp slop inflated ~25x): superset
  // collection is harmless since the final select uses exact keys.
  float X[QPW];
#pragma unroll
  for (int r = 0; r < QPW; ++r) {
    float slop = 6e-6f * (fabsf(xxq[r]) + fabsf(pT[r])) + 1e-5f;
    X[r] = fminf(pT[r], xxq[r]) - 2.0f * slop;
  }

  // ---- scan 2 (global-direct): collect survivors (proxy >= X), exact-d keys ----
  for (int j0 = 0; j0 < N_; j0 += 128) {
    const int ia = j0 + lane;
    const int ib = ia + 64;
    float4 ca = cg[ia];
    float4 cb2 = cg[ib];
#pragma unroll
    for (int r = 0; r < QPW; ++r) {
      float pa = PROXY(r, ca);
      float pb = PROXY(r, cb2);
      if (pa >= X[r]) {
        float d = exact_d(qx[r], qy[r], qz[r], xxq[r], ca);
        int pos = atomicAdd(&scnt[w * QPW + r], 1);
        if (pos < CAP) sbuf[w * QPW + r][pos] = pack_key_u64(d, ia);
      }
      if (pb >= X[r]) {
        float d = exact_d(qx[r], qy[r], qz[r], xxq[r], cb2);
        int pos = atomicAdd(&scnt[w * QPW + r], 1);
        if (pos < CAP) sbuf[w * QPW + r][pos] = pack_key_u64(d, ib);
      }
    }
  }
  __syncthreads();

  // ---- exact select: 32 lanes per query, insert16 over survivors, merge ----
  const int qsel = t >> 5;             // 0..15: query within block
  const int s32 = t & 31;              // lane within 32-lane select group
  const int n = qbase + qsel;

  double hd[16];
#pragma unroll
  for (int i = 0; i < 16; ++i) hd[i] = __builtin_bit_cast(double, SENT_U64);

  const int cntv = scnt[qsel];
  if (cntv > CAP) {
    // overflow fallback (never expected): exact rescan from global, raw formula
    float fqx = cb[n * 3 + 0], fqy = cb[n * 3 + 1], fqz = cb[n * 3 + 2];
    float fxx = sq3(fqx, fqy, fqz);
    for (int j = s32; j < N_; j += 32) {
      float cx = cb[j * 3 + 0], cy = cb[j * 3 + 1], cz = cb[j * 3 + 2];
      float ww = sq3(cx, cy, cz);
      float dot = fmaf(fqz, cz, fmaf(fqy, cy, fqx * cx));
      float d2;
      {
#pragma clang fp contract(off)
        d2 = (fxx + ww) - 2.0f * dot;
      }
      d2 = fmaxf(d2, 0.0f);
      double k = __builtin_bit_cast(double, pack_key_u64(d2, j));
      if (k < hd[15]) insert16(hd, k);
    }
  } else {
    for (int i = s32; i < cntv; i += 32) {
      double k = __builtin_bit_cast(double, (uint64_t)sbuf[qsel][i]);
      if (k < hd[15]) insert16(hd, k);
    }
  }

  // merge the 32 per-lane sorted lists -> top-16 (ascending (dist,idx))
  int* myout = idxout + ((size_t)(bb * N_ + n)) * K_;
#pragma unroll
  for (int r = 0; r < 16; ++r) {
    double v = hd[0];
    v = fmin(v, shfl_xor_f64(v, 1));
    v = fmin(v, shfl_xor_f64(v, 2));
    v = fmin(v, shfl_xor_f64(v, 4));
    v = fmin(v, shfl_xor_f64(v, 8));
    v = fmin(v, shfl_xor_f64(v, 16));
    if (__builtin_bit_cast(uint64_t, hd[0]) == __builtin_bit_cast(uint64_t, v)) {
#pragma unroll
      for (int z = 0; z < 15; ++z) hd[z] = hd[z + 1];
      hd[15] = __builtin_bit_cast(double, SENT_U64);
    }
    if (s32 == 0) myout[r] = (int)(uint32_t)__builtin_bit_cast(uint64_t, v);
  }
}

// ---------------- stage 2: gather + (16x131)@(131x64) + relu + max_k ----------------
__global__ __launch_bounds__(256) void stage2(const float* __restrict__ coords,
                                              const float* __restrict__ feat,
                                              const int* __restrict__ idxbuf,
                                              const __hip_bfloat16* __restrict__ wfrag,
                                              const float* __restrict__ bias,
                                              float* __restrict__ out) {
  __shared__ __align__(16) __hip_bfloat16 xs[4][16][XS_STRIDE];
  const int t = threadIdx.x;
  const int w = t >> 6;
  const int lane = t & 63;
  const int q = blockIdx.x * 4 + w;
  const int bb = q >> 13;
  const int n = q & (N_ - 1);
  const float* cb = coords + (size_t)bb * N_ * 3;
  const float* fb = feat + (size_t)bb * N_ * C_;
  const int* myidx = idxbuf + (size_t)q * K_;

  float fi = fb[(size_t)n * C_ + lane];
  float qc = (lane < 3) ? cb[n * 3 + lane] : 0.0f;

#pragma unroll
  for (int k = 0; k < K_; ++k) {
    int nb = myidx[k];
    float nf = fb[(size_t)nb * C_ + lane];
    xs[w][k][lane] = __float2bfloat16(fi);
    xs[w][k][C_ + lane] = __float2bfloat16(nf - fi);
    if (lane < 3) {
      xs[w][k][128 + lane] = __float2bfloat16(cb[nb * 3 + lane] - qc);
    } else if (lane < 40) {
      xs[w][k][128 + lane] = __float2bfloat16(0.0f);  // zero-pad d = 131..167
    }
  }
  __syncthreads();

  const int row = lane & 15;   // = output channel within 16-col tile (D's col)
  const int g = lane >> 4;
  short8v a[5];
#pragma unroll
  for (int ks = 0; ks < 5; ++ks)
    a[ks] = *(const short8v*)&xs[w][row][ks * 32 + g * 8];

  const short8v* wf = (const short8v*)wfrag;
#pragma unroll
  for (int nt = 0; nt < 4; ++nt) {
    f32x4 acc = {0.f, 0.f, 0.f, 0.f};
#pragma unroll
    for (int ks = 0; ks < 5; ++ks) {
      short8v bf = wf[(nt * 5 + ks) * 64 + lane];
      acc = __builtin_amdgcn_mfma_f32_16x16x32_bf16(a[ks], bf, acc, 0, 0, 0);
    }
    float bcol = bias[nt * 16 + row];
    float m = fmaxf(fmaxf(fmaxf(acc[0] + bcol, 0.f), fmaxf(acc[1] + bcol, 0.f)),
                    fmaxf(fmaxf(acc[2] + bcol, 0.f), fmaxf(acc[3] + bcol, 0.f)));
    m = fmaxf(m, __shfl_xor(m, 16, 64));
    m = fmaxf(m, __shfl_xor(m, 32, 64));
    if (lane < 16) out[(size_t)q * C_ + nt * 16 + row] = m;
  }
}

extern "C" void kernel_launch(void* const* d_in, const int* in_sizes, int n_in,
                              void* d_out, int out_size, void* d_ws, size_t ws_size,
                              hipStream_t stream) {
  const float* coords = (const float*)d_in[0];
  const float* feat = (const float*)d_in[1];
  const float* W = (const float*)d_in[2];
  const float* bias = (const float*)d_in[3];
  float* out = (float*)d_out;

  int* ws_idx = (int*)d_ws;                                   // B*N*K ints = 1 MiB
  char* p = (char*)d_ws + (size_t)B_ * N_ * K_ * sizeof(int);
  __hip_bfloat16* wfrag = (__hip_bfloat16*)p;                 // 20 KiB
  float4* c4 = (float4*)(p + 32768);                          // 256 KiB, 16B-aligned

  const int prep_elems = 4 * 5 * 64 * 8 + B_ * N_;
  prep<<<(prep_elems + 255) / 256, 256, 0, stream>>>(coords, W, wfrag, c4);
  knn_kernel<<<(B_ * N_) / QPB, 512, 0, stream>>>(coords, c4, ws_idx);
  stage2<<<(B_ * N_) / 4, 256, 0, stream>>>(coords, feat, ws_idx, wfrag, bias, out);
}

// Round 20
// 121.894 us; speedup vs baseline: 1.0138x; 1.0138x over previous
//
#include <hip/hip_runtime.h>
#include <hip/hip_bf16.h>
#include <stdint.h>
#include <float.h>

#define B_ 2
#define N_ 8192
#define C_ 64
#define K_ 16
#define D_IN 131     // 2C+3
#define XS_STRIDE 168
#define QPB 16       // queries per block (4 waves; wave-pairs share 8 queries)
#define QPW 8        // queries per wave (each wave scans HALF the candidates)
#define HALF_N (N_ / 2)
#define CAP 128      // survivor buffer capacity per query

typedef __attribute__((ext_vector_type(8))) short short8v;
typedef __attribute__((ext_vector_type(4))) float f32x4;
typedef unsigned long long ull;

// sentinel: larger than any real key, but FINITE as f64 (NaN would break fmin/fmax)
#define SENT_U64 0x7F7FFFFFFFFFFFFFull

__device__ __forceinline__ float sq3(float x, float y, float z) {
#pragma clang fp contract(off)
  return (x * x + y * y) + z * z;
}

__device__ __forceinline__ uint64_t shfl_xor_u64(uint64_t x, int mask) {
  int lo = __shfl_xor((int)(uint32_t)(x & 0xffffffffull), mask, 64);
  int hi = __shfl_xor((int)(uint32_t)(x >> 32), mask, 64);
  return ((uint64_t)(uint32_t)hi << 32) | (uint32_t)lo;
}

__device__ __forceinline__ double shfl_xor_f64(double x, int mask) {
  return __builtin_bit_cast(double, shfl_xor_u64(__builtin_bit_cast(uint64_t, x), mask));
}

__device__ __forceinline__ uint64_t pack_key_u64(float d, int idx) {
  return ((uint64_t)__float_as_uint(d) << 32) | (uint32_t)idx;
}

// branchless sorted-insert: precondition key < hd[15]; 15-stage min/max ladder.
__device__ __forceinline__ void insert16(double* hd, double key) {
  hd[15] = key;
#pragma unroll
  for (int z = 15; z >= 1; --z) {
    double a = hd[z - 1], b = hd[z];
    hd[z - 1] = fmin(a, b);
    hd[z] = fmax(a, b);
  }
}

// exact reference distance (bit-identical to all passing rounds)
__device__ __forceinline__ float exact_d(float qx, float qy, float qz, float xxq,
                                         float4 cd) {
  float dot2 = fmaf(qz, cd.z, fmaf(qy, cd.y, qx * cd.x));
  float dtmp;
  {
#pragma clang fp contract(off)
    dtmp = (xxq + cd.w) - dot2;
  }
  return fmaxf(dtmp, 0.0f);
}

// ---- merged prep: W -> bf16 fragments, coords -> c4 = (2cx,2cy,2cz,|c|^2) ----
__global__ __launch_bounds__(256) void prep(const float* __restrict__ coords,
                                            const float* __restrict__ W,
                                            __hip_bfloat16* __restrict__ wfrag,
                                            float4* __restrict__ c4) {
  int i = blockIdx.x * 256 + threadIdx.x;
  if (i < 4 * 5 * 64 * 8) {
    int j = i & 7;
    int l = (i >> 3) & 63;
    int ks = (i >> 9) % 5;
    int nt = (i >> 9) / 5;
    int k = ks * 32 + (l >> 4) * 8 + j;
    int col = nt * 16 + (l & 15);
    float v = (k < D_IN) ? W[k * 64 + col] : 0.0f;
    wfrag[i] = __float2bfloat16(v);
  }
  int j2 = i - 4 * 5 * 64 * 8;
  if (j2 >= 0 && j2 < B_ * N_) {
    float cx = coords[j2 * 3 + 0], cy = coords[j2 * 3 + 1], cz = coords[j2 * 3 + 2];
    c4[j2] = make_float4(2.0f * cx, 2.0f * cy, 2.0f * cz, sq3(cx, cy, cz));
  }
}

// ---- KNN: split-candidate scan. Wave pair shares 8 queries; each wave scans half N ----
__global__ __launch_bounds__(256) void knn_kernel(const float* __restrict__ coords,
                                                  const float4* __restrict__ c4,
                                                  int* __restrict__ idxout) {
  __shared__ ull sbuf[QPB][CAP];
  __shared__ int scnt[QPB];
  __shared__ float Mx[2][2][64][9];   // [qgroup][half][lane][r], stride-9 pad
  const int t = threadIdx.x;
  const int w = t >> 6;                // wave 0..3
  const int lane = t & 63;
  const int half = w & 1;              // candidate half this wave scans
  const int qg = w >> 1;               // query group (0: q0-7, 1: q8-15)
  const int blk = blockIdx.x;          // 1024 blocks: 512 per batch
  const int bb = blk >> 9;
  const int qbase = (blk & 511) * QPB;
  const float* cb = coords + (size_t)bb * N_ * 3;
  const float4* cg = c4 + (size_t)bb * N_;
  const int cbase = half * HALF_N;     // this wave's candidate range start

  // this wave's 8 queries in registers (raw coords)
  float qx[QPW], qy[QPW], qz[QPW], xxq[QPW];
#pragma unroll
  for (int r = 0; r < QPW; ++r) {
    int n = qbase + qg * QPW + r;
    qx[r] = cb[n * 3 + 0]; qy[r] = cb[n * 3 + 1]; qz[r] = cb[n * 3 + 2];
    xxq[r] = sq3(qx[r], qy[r], qz[r]);
  }
  if (t < QPB) scnt[t] = 0;

// proxy = q.(2c) - w : 3 fma (the -w rides the innermost fma operand-negation)
#define PROXY(r, cd) fmaf(qz[r], (cd).z, fmaf(qy[r], (cd).y, fmaf(qx[r], (cd).x, -(cd).w)))

  // ---- scan 1 (global-direct over this wave's half): per-lane MAX proxy ----
  float M[QPW];
#pragma unroll
  for (int r = 0; r < QPW; ++r) M[r] = -FLT_MAX;

  for (int j0 = 0; j0 < HALF_N; j0 += 256) {
    float4 ca = cg[cbase + j0 + lane];
    float4 cb2 = cg[cbase + j0 + 64 + lane];
    float4 cc = cg[cbase + j0 + 128 + lane];
    float4 cd = cg[cbase + j0 + 192 + lane];
#pragma unroll
    for (int r = 0; r < QPW; ++r) {
      float p0 = PROXY(r, ca);
      float p1 = PROXY(r, cb2);
      float p2 = PROXY(r, cc);
      float p3 = PROXY(r, cd);
      M[r] = fmaxf(M[r], fmaxf(fmaxf(p0, p1), fmaxf(p2, p3)));
    }
  }

  // ---- cross-wave combine: partner wave scanned the other half ----
#pragma unroll
  for (int r = 0; r < QPW; ++r) Mx[qg][half][lane][r] = M[r];
  __syncthreads();
#pragma unroll
  for (int r = 0; r < QPW; ++r) M[r] = fmaxf(M[r], Mx[qg][half ^ 1][lane][r]);

  // ---- threshold: 16th LARGEST of the 64 combined lane-maxima per query ----
  // (each combined lane-max is one distinct candidate => >=16 distinct >= pT)
  float A[QPW], pT[QPW];
#pragma unroll
  for (int r = 0; r < QPW; ++r) { A[r] = M[r]; pT[r] = -FLT_MAX; }
#pragma unroll
  for (int rd = 0; rd < 16; ++rd) {
#pragma unroll
    for (int r = 0; r < QPW; ++r) {
      float g = A[r];
      g = fmaxf(g, __shfl_xor(g, 1, 64));
      g = fmaxf(g, __shfl_xor(g, 2, 64));
      g = fmaxf(g, __shfl_xor(g, 4, 64));
      g = fmaxf(g, __shfl_xor(g, 8, 64));
      g = fmaxf(g, __shfl_xor(g, 16, 64));
      g = fmaxf(g, __shfl_xor(g, 32, 64));
      pT[r] = g;
      A[r] = (A[r] == g) ? -FLT_MAX : A[r];
    }
  }
  // conservative proxy threshold X (few-ulp slop inflated ~25x): superset
  // collection is harmless since the final select uses exact keys.
  float X[QPW];
#pragma unroll
  for (int r = 0; r < QPW; ++r) {
    float slop = 6e-6f * (fabsf(xxq[r]) + fabsf(pT[r])) + 1e-5f;
    X[r] = fminf(pT[r], xxq[r]) - 2.0f * slop;
  }

  // ---- scan 2 (this wave's half): collect survivors (proxy >= X), exact-d keys ----
  for (int j0 = 0; j0 < HALF_N; j0 += 128) {
    const int ia = cbase + j0 + lane;
    const int ib = ia + 64;
    float4 ca = cg[ia];
    float4 cb2 = cg[ib];
#pragma unroll
    for (int r = 0; r < QPW; ++r) {
      float pa = PROXY(r, ca);
      float pb = PROXY(r, cb2);
      if (pa >= X[r]) {
        float d = exact_d(qx[r], qy[r], qz[r], xxq[r], ca);
        int pos = atomicAdd(&scnt[qg * QPW + r], 1);
        if (pos < CAP) sbuf[qg * QPW + r][pos] = pack_key_u64(d, ia);
      }
      if (pb >= X[r]) {
        float d = exact_d(qx[r], qy[r], qz[r], xxq[r], cb2);
        int pos = atomicAdd(&scnt[qg * QPW + r], 1);
        if (pos < CAP) sbuf[qg * QPW + r][pos] = pack_key_u64(d, ib);
      }
    }
  }
  __syncthreads();

  // ---- exact select: 16 lanes per query, insert16 over survivors, merge ----
  const int qloc = t >> 4;             // 0..15: query within block
  const int s16 = t & 15;              // lane within 16-lane select group
  const int n = qbase + qloc;

  double hd[16];
#pragma unroll
  for (int i = 0; i < 16; ++i) hd[i] = __builtin_bit_cast(double, SENT_U64);

  const int cntv = scnt[qloc];
  if (cntv > CAP) {
    // overflow fallback (never expected): exact rescan from global, raw formula
    float fqx = cb[n * 3 + 0], fqy = cb[n * 3 + 1], fqz = cb[n * 3 + 2];
    float fxx = sq3(fqx, fqy, fqz);
    for (int j = s16; j < N_; j += 16) {
      float cx = cb[j * 3 + 0], cy = cb[j * 3 + 1], cz = cb[j * 3 + 2];
      float ww = sq3(cx, cy, cz);
      float dot = fmaf(fqz, cz, fmaf(fqy, cy, fqx * cx));
      float d2;
      {
#pragma clang fp contract(off)
        d2 = (fxx + ww) - 2.0f * dot;
      }
      d2 = fmaxf(d2, 0.0f);
      double k = __builtin_bit_cast(double, pack_key_u64(d2, j));
      if (k < hd[15]) insert16(hd, k);
    }
  } else {
    for (int i = s16; i < cntv; i += 16) {
      double k = __builtin_bit_cast(double, (uint64_t)sbuf[qloc][i]);
      if (k < hd[15]) insert16(hd, k);
    }
  }

  // merge the 16 per-lane sorted lists -> top-16 (ascending (dist,idx))
  int* myout = idxout + ((size_t)(bb * N_ + n)) * K_;
#pragma unroll
  for (int r = 0; r < 16; ++r) {
    double v = hd[0];
    v = fmin(v, shfl_xor_f64(v, 1));
    v = fmin(v, shfl_xor_f64(v, 2));
    v = fmin(v, shfl_xor_f64(v, 4));
    v = fmin(v, shfl_xor_f64(v, 8));
    if (__builtin_bit_cast(uint64_t, hd[0]) == __builtin_bit_cast(uint64_t, v)) {
#pragma unroll
      for (int z = 0; z < 15; ++z) hd[z] = hd[z + 1];
      hd[15] = __builtin_bit_cast(double, SENT_U64);
    }
    if (s16 == 0) myout[r] = (int)(uint32_t)__builtin_bit_cast(uint64_t, v);
  }
}

// ---------------- stage 2: gather + (16x131)@(131x64) + relu + max_k ----------------
__global__ __launch_bounds__(256) void stage2(const float* __restrict__ coords,
                                              const float* __restrict__ feat,
                                              const int* __restrict__ idxbuf,
                                              const __hip_bfloat16* __restrict__ wfrag,
                                              const float* __restrict__ bias,
                                              float* __restrict__ out) {
  __shared__ __align__(16) __hip_bfloat16 xs[4][16][XS_STRIDE];
  const int t = threadIdx.x;
  const int w = t >> 6;
  const int lane = t & 63;
  const int q = blockIdx.x * 4 + w;
  const int bb = q >> 13;
  const int n = q & (N_ - 1);
  const float* cb = coords + (size_t)bb * N_ * 3;
  const float* fb = feat + (size_t)bb * N_ * C_;
  const int* myidx = idxbuf + (size_t)q * K_;

  float fi = fb[(size_t)n * C_ + lane];
  float qc = (lane < 3) ? cb[n * 3 + lane] : 0.0f;

#pragma unroll
  for (int k = 0; k < K_; ++k) {
    int nb = myidx[k];
    float nf = fb[(size_t)nb * C_ + lane];
    xs[w][k][lane] = __float2bfloat16(fi);
    xs[w][k][C_ + lane] = __float2bfloat16(nf - fi);
    if (lane < 3) {
      xs[w][k][128 + lane] = __float2bfloat16(cb[nb * 3 + lane] - qc);
    } else if (lane < 40) {
      xs[w][k][128 + lane] = __float2bfloat16(0.0f);  // zero-pad d = 131..167
    }
  }
  __syncthreads();

  const int row = lane & 15;   // = output channel within 16-col tile (D's col)
  const int g = lane >> 4;
  short8v a[5];
#pragma unroll
  for (int ks = 0; ks < 5; ++ks)
    a[ks] = *(const short8v*)&xs[w][row][ks * 32 + g * 8];

  const short8v* wf = (const short8v*)wfrag;
#pragma unroll
  for (int nt = 0; nt < 4; ++nt) {
    f32x4 acc = {0.f, 0.f, 0.f, 0.f};
#pragma unroll
    for (int ks = 0; ks < 5; ++ks) {
      short8v bf = wf[(nt * 5 + ks) * 64 + lane];
      acc = __builtin_amdgcn_mfma_f32_16x16x32_bf16(a[ks], bf, acc, 0, 0, 0);
    }
    float bcol = bias[nt * 16 + row];
    float m = fmaxf(fmaxf(fmaxf(acc[0] + bcol, 0.f), fmaxf(acc[1] + bcol, 0.f)),
                    fmaxf(fmaxf(acc[2] + bcol, 0.f), fmaxf(acc[3] + bcol, 0.f)));
    m = fmaxf(m, __shfl_xor(m, 16, 64));
    m = fmaxf(m, __shfl_xor(m, 32, 64));
    if (lane < 16) out[(size_t)q * C_ + nt * 16 + row] = m;
  }
}

extern "C" void kernel_launch(void* const* d_in, const int* in_sizes, int n_in,
                              void* d_out, int out_size, void* d_ws, size_t ws_size,
                              hipStream_t stream) {
  const float* coords = (const float*)d_in[0];
  const float* feat = (const float*)d_in[1];
  const float* W = (const float*)d_in[2];
  const float* bias = (const float*)d_in[3];
  float* out = (float*)d_out;

  int* ws_idx = (int*)d_ws;                                   // B*N*K ints = 1 MiB
  char* p = (char*)d_ws + (size_t)B_ * N_ * K_ * sizeof(int);
  __hip_bfloat16* wfrag = (__hip_bfloat16*)p;                 // 20 KiB
  float4* c4 = (float4*)(p + 32768);                          // 256 KiB, 16B-aligned

  const int prep_elems = 4 * 5 * 64 * 8 + B_ * N_;
  prep<<<(prep_elems + 255) / 256, 256, 0, stream>>>(coords, W, wfrag, c4);
  knn_kernel<<<(B_ * N_) / QPB, 256, 0, stream>>>(coords, c4, ws_idx);
  stage2<<<(B_ * N_) / 4, 256, 0, stream>>>(coords, feat, ws_idx, wfrag, bias, out);
}

// Round 21
// 110.141 us; speedup vs baseline: 1.1219x; 1.1067x over previous
//
#include <hip/hip_runtime.h>
#include <hip/hip_bf16.h>
#include <stdint.h>
#include <float.h>

#define B_ 2
#define N_ 8192
#define C_ 64
#define K_ 16
#define D_IN 131     // 2C+3
#define XS_STRIDE 168
#define QPB 16       // queries per block (4 waves x 4 queries)
#define QPW 4        // queries per wave
#define CAP 128      // survivor buffer capacity per query

typedef __attribute__((ext_vector_type(8))) short short8v;
typedef __attribute__((ext_vector_type(4))) float f32x4;
typedef unsigned long long ull;

// sentinel: larger than any real key, but FINITE as f64 (NaN would break fmin/fmax)
#define SENT_U64 0x7F7FFFFFFFFFFFFFull

__device__ __forceinline__ float sq3(float x, float y, float z) {
#pragma clang fp contract(off)
  return (x * x + y * y) + z * z;
}

__device__ __forceinline__ uint64_t shfl_xor_u64(uint64_t x, int mask) {
  int lo = __shfl_xor((int)(uint32_t)(x & 0xffffffffull), mask, 64);
  int hi = __shfl_xor((int)(uint32_t)(x >> 32), mask, 64);
  return ((uint64_t)(uint32_t)hi << 32) | (uint32_t)lo;
}

__device__ __forceinline__ double shfl_xor_f64(double x, int mask) {
  return __builtin_bit_cast(double, shfl_xor_u64(__builtin_bit_cast(uint64_t, x), mask));
}

__device__ __forceinline__ uint64_t pack_key_u64(float d, int idx) {
  return ((uint64_t)__float_as_uint(d) << 32) | (uint32_t)idx;
}

// branchless sorted-insert: precondition key < hd[15]; 15-stage min/max ladder.
__device__ __forceinline__ void insert16(double* hd, double key) {
  hd[15] = key;
#pragma unroll
  for (int z = 15; z >= 1; --z) {
    double a = hd[z - 1], b = hd[z];
    hd[z - 1] = fmin(a, b);
    hd[z] = fmax(a, b);
  }
}

// exact reference distance (bit-identical to all passing rounds)
__device__ __forceinline__ float exact_d(float qx, float qy, float qz, float xxq,
                                         float4 cd) {
  float dot2 = fmaf(qz, cd.z, fmaf(qy, cd.y, qx * cd.x));
  float dtmp;
  {
#pragma clang fp contract(off)
    dtmp = (xxq + cd.w) - dot2;
  }
  return fmaxf(dtmp, 0.0f);
}

// ---- merged prep: W -> bf16 fragments, coords -> c4 = (2cx,2cy,2cz,|c|^2) ----
__global__ __launch_bounds__(256) void prep(const float* __restrict__ coords,
                                            const float* __restrict__ W,
                                            __hip_bfloat16* __restrict__ wfrag,
                                            float4* __restrict__ c4) {
  int i = blockIdx.x * 256 + threadIdx.x;
  if (i < 4 * 5 * 64 * 8) {
    int j = i & 7;
    int l = (i >> 3) & 63;
    int ks = (i >> 9) % 5;
    int nt = (i >> 9) / 5;
    int k = ks * 32 + (l >> 4) * 8 + j;
    int col = nt * 16 + (l & 15);
    float v = (k < D_IN) ? W[k * 64 + col] : 0.0f;
    wfrag[i] = __float2bfloat16(v);
  }
  int j2 = i - 4 * 5 * 64 * 8;
  if (j2 >= 0 && j2 < B_ * N_) {
    float cx = coords[j2 * 3 + 0], cy = coords[j2 * 3 + 1], cz = coords[j2 * 3 + 2];
    c4[j2] = make_float4(2.0f * cx, 2.0f * cy, 2.0f * cz, sq3(cx, cy, cz));
  }
}

// ---------------- KNN: global-direct scans, idx-only push ----------------
__global__ __launch_bounds__(256) void knn_kernel(const float* __restrict__ coords,
                                                  const float4* __restrict__ c4,
                                                  int* __restrict__ idxout) {
  __shared__ int sbuf[QPB][CAP];
  __shared__ int scnt[QPB];
  const int t = threadIdx.x;
  const int w = t >> 6;                // wave 0..3
  const int lane = t & 63;
  const int blk = blockIdx.x;          // 1024 blocks: 512 per batch
  const int bb = blk >> 9;
  const int qbase = (blk & 511) * QPB;
  const float* cb = coords + (size_t)bb * N_ * 3;
  const float4* cg = c4 + (size_t)bb * N_;

  // this wave's 4 queries in registers (raw coords)
  float qx[QPW], qy[QPW], qz[QPW], xxq[QPW];
#pragma unroll
  for (int r = 0; r < QPW; ++r) {
    int n = qbase + w * QPW + r;
    qx[r] = cb[n * 3 + 0]; qy[r] = cb[n * 3 + 1]; qz[r] = cb[n * 3 + 2];
    xxq[r] = sq3(qx[r], qy[r], qz[r]);
  }
  if (t < QPB) scnt[t] = 0;
  __syncthreads();  // scnt visible before scan-2 pushes

// proxy = q.(2c) - w : 3 fma (the -w rides the innermost fma operand-negation)
#define PROXY(r, cd) fmaf(qz[r], (cd).z, fmaf(qy[r], (cd).y, fmaf(qx[r], (cd).x, -(cd).w)))

  // ---- scan 1 (global-direct, 4-deep ILP): per-lane running MAX proxy ----
  float M[QPW];
#pragma unroll
  for (int r = 0; r < QPW; ++r) M[r] = -FLT_MAX;

  for (int j0 = 0; j0 < N_; j0 += 256) {
    float4 ca = cg[j0 + lane];
    float4 cb2 = cg[j0 + 64 + lane];
    float4 cc = cg[j0 + 128 + lane];
    float4 cd = cg[j0 + 192 + lane];
#pragma unroll
    for (int r = 0; r < QPW; ++r) {
      float p0 = PROXY(r, ca);
      float p1 = PROXY(r, cb2);
      float p2 = PROXY(r, cc);
      float p3 = PROXY(r, cd);
      M[r] = fmaxf(M[r], fmaxf(fmaxf(p0, p1), fmaxf(p2, p3)));
    }
  }

  // ---- threshold: 16th LARGEST of the 64 lane-maxima per query ----
  float A[QPW], pT[QPW];
#pragma unroll
  for (int r = 0; r < QPW; ++r) { A[r] = M[r]; pT[r] = -FLT_MAX; }
#pragma unroll
  for (int rd = 0; rd < 16; ++rd) {
#pragma unroll
    for (int r = 0; r < QPW; ++r) {
      float g = A[r];
      g = fmaxf(g, __shfl_xor(g, 1, 64));
      g = fmaxf(g, __shfl_xor(g, 2, 64));
      g = fmaxf(g, __shfl_xor(g, 4, 64));
      g = fmaxf(g, __shfl_xor(g, 8, 64));
      g = fmaxf(g, __shfl_xor(g, 16, 64));
      g = fmaxf(g, __shfl_xor(g, 32, 64));
      pT[r] = g;
      A[r] = (A[r] == g) ? -FLT_MAX : A[r];
    }
  }
  // conservative proxy threshold X (few-ulp slop inflated ~25x): superset
  // collection is harmless since the final select uses exact keys.
  float X[QPW];
#pragma unroll
  for (int r = 0; r < QPW; ++r) {
    float slop = 6e-6f * (fabsf(xxq[r]) + fabsf(pT[r])) + 1e-5f;
    X[r] = fminf(pT[r], xxq[r]) - 2.0f * slop;
  }

  // ---- scan 2 (4-deep ILP): push INDEX only for survivors (proxy >= X) ----
  for (int j0 = 0; j0 < N_; j0 += 256) {
    const int ia = j0 + lane;
    float4 ca = cg[ia];
    float4 cb2 = cg[ia + 64];
    float4 cc = cg[ia + 128];
    float4 cd = cg[ia + 192];
#pragma unroll
    for (int r = 0; r < QPW; ++r) {
      float p0 = PROXY(r, ca);
      float p1 = PROXY(r, cb2);
      float p2 = PROXY(r, cc);
      float p3 = PROXY(r, cd);
      const int qr = w * QPW + r;
      if (p0 >= X[r]) { int pos = atomicAdd(&scnt[qr], 1); if (pos < CAP) sbuf[qr][pos] = ia; }
      if (p1 >= X[r]) { int pos = atomicAdd(&scnt[qr], 1); if (pos < CAP) sbuf[qr][pos] = ia + 64; }
      if (p2 >= X[r]) { int pos = atomicAdd(&scnt[qr], 1); if (pos < CAP) sbuf[qr][pos] = ia + 128; }
      if (p3 >= X[r]) { int pos = atomicAdd(&scnt[qr], 1); if (pos < CAP) sbuf[qr][pos] = ia + 192; }
    }
  }
  __syncthreads();

  // ---- exact select: 16 lanes per query; recompute exact-d per survivor ----
  const int qloc = t >> 4;             // 0..15: query within block
  const int s16 = t & 15;              // lane within 16-lane select group
  const int n = qbase + qloc;

  // this select-group's query coords (may differ from scan queries)
  const float fqx = cb[n * 3 + 0], fqy = cb[n * 3 + 1], fqz = cb[n * 3 + 2];
  const float fxx = sq3(fqx, fqy, fqz);

  double hd[16];
#pragma unroll
  for (int i = 0; i < 16; ++i) hd[i] = __builtin_bit_cast(double, SENT_U64);

  const int cntv = scnt[qloc];
  if (cntv > CAP) {
    // overflow fallback (never expected): exact rescan from global, raw formula
    for (int j = s16; j < N_; j += 16) {
      float cx = cb[j * 3 + 0], cy = cb[j * 3 + 1], cz = cb[j * 3 + 2];
      float ww = sq3(cx, cy, cz);
      float dot = fmaf(fqz, cz, fmaf(fqy, cy, fqx * cx));
      float d2;
      {
#pragma clang fp contract(off)
        d2 = (fxx + ww) - 2.0f * dot;
      }
      d2 = fmaxf(d2, 0.0f);
      double k = __builtin_bit_cast(double, pack_key_u64(d2, j));
      if (k < hd[15]) insert16(hd, k);
    }
  } else {
    for (int i = s16; i < cntv; i += 16) {
      int idx = sbuf[qloc][i];
      float d = exact_d(fqx, fqy, fqz, fxx, cg[idx]);
      double k = __builtin_bit_cast(double, pack_key_u64(d, idx));
      if (k < hd[15]) insert16(hd, k);
    }
  }

  // merge the 16 per-lane sorted lists -> top-16 (ascending (dist,idx))
  int* myout = idxout + ((size_t)(bb * N_ + n)) * K_;
#pragma unroll
  for (int r = 0; r < 16; ++r) {
    double v = hd[0];
    v = fmin(v, shfl_xor_f64(v, 1));
    v = fmin(v, shfl_xor_f64(v, 2));
    v = fmin(v, shfl_xor_f64(v, 4));
    v = fmin(v, shfl_xor_f64(v, 8));
    if (__builtin_bit_cast(uint64_t, hd[0]) == __builtin_bit_cast(uint64_t, v)) {
#pragma unroll
      for (int z = 0; z < 15; ++z) hd[z] = hd[z + 1];
      hd[15] = __builtin_bit_cast(double, SENT_U64);
    }
    if (s16 == 0) myout[r] = (int)(uint32_t)__builtin_bit_cast(uint64_t, v);
  }
}

// ---------------- stage 2: gather + (16x131)@(131x64) + relu + max_k ----------------
__global__ __launch_bounds__(256) void stage2(const float* __restrict__ coords,
                                              const float* __restrict__ feat,
                                              const int* __restrict__ idxbuf,
                                              const __hip_bfloat16* __restrict__ wfrag,
                                              const float* __restrict__ bias,
                                              float* __restrict__ out) {
  __shared__ __align__(16) __hip_bfloat16 xs[4][16][XS_STRIDE];
  const int t = threadIdx.x;
  const int w = t >> 6;
  const int lane = t & 63;
  const int q = blockIdx.x * 4 + w;
  const int bb = q >> 13;
  const int n = q & (N_ - 1);
  const float* cb = coords + (size_t)bb * N_ * 3;
  const float* fb = feat + (size_t)bb * N_ * C_;
  const int* myidx = idxbuf + (size_t)q * K_;

  float fi = fb[(size_t)n * C_ + lane];
  float qc = (lane < 3) ? cb[n * 3 + lane] : 0.0f;

#pragma unroll
  for (int k = 0; k < K_; ++k) {
    int nb = myidx[k];
    float nf = fb[(size_t)nb * C_ + lane];
    xs[w][k][lane] = __float2bfloat16(fi);
    xs[w][k][C_ + lane] = __float2bfloat16(nf - fi);
    if (lane < 3) {
      xs[w][k][128 + lane] = __float2bfloat16(cb[nb * 3 + lane] - qc);
    } else if (lane < 40) {
      xs[w][k][128 + lane] = __float2bfloat16(0.0f);  // zero-pad d = 131..167
    }
  }
  __syncthreads();

  const int row = lane & 15;   // = output channel within 16-col tile (D's col)
  const int g = lane >> 4;
  short8v a[5];
#pragma unroll
  for (int ks = 0; ks < 5; ++ks)
    a[ks] = *(const short8v*)&xs[w][row][ks * 32 + g * 8];

  const short8v* wf = (const short8v*)wfrag;
#pragma unroll
  for (int nt = 0; nt < 4; ++nt) {
    f32x4 acc = {0.f, 0.f, 0.f, 0.f};
#pragma unroll
    for (int ks = 0; ks < 5; ++ks) {
      short8v bf = wf[(nt * 5 + ks) * 64 + lane];
      acc = __builtin_amdgcn_mfma_f32_16x16x32_bf16(a[ks], bf, acc, 0, 0, 0);
    }
    float bcol = bias[nt * 16 + row];
    float m = fmaxf(fmaxf(fmaxf(acc[0] + bcol, 0.f), fmaxf(acc[1] + bcol, 0.f)),
                    fmaxf(fmaxf(acc[2] + bcol, 0.f), fmaxf(acc[3] + bcol, 0.f)));
    m = fmaxf(m, __shfl_xor(m, 16, 64));
    m = fmaxf(m, __shfl_xor(m, 32, 64));
    if (lane < 16) out[(size_t)q * C_ + nt * 16 + row] = m;
  }
}

extern "C" void kernel_launch(void* const* d_in, const int* in_sizes, int n_in,
                              void* d_out, int out_size, void* d_ws, size_t ws_size,
                              hipStream_t stream) {
  const float* coords = (const float*)d_in[0];
  const float* feat = (const float*)d_in[1];
  const float* W = (const float*)d_in[2];
  const float* bias = (const float*)d_in[3];
  float* out = (float*)d_out;

  int* ws_idx = (int*)d_ws;                                   // B*N*K ints = 1 MiB
  char* p = (char*)d_ws + (size_t)B_ * N_ * K_ * sizeof(int);
  __hip_bfloat16* wfrag = (__hip_bfloat16*)p;                 // 20 KiB
  float4* c4 = (float4*)(p + 32768);                          // 256 KiB, 16B-aligned

  const int prep_elems = 4 * 5 * 64 * 8 + B_ * N_;
  prep<<<(prep_elems + 255) / 256, 256, 0, stream>>>(coords, W, wfrag, c4);
  knn_kernel<<<(B_ * N_) / QPB, 256, 0, stream>>>(coords, c4, ws_idx);
  stage2<<<(B_ * N_) / 4, 256, 0, stream>>>(coords, feat, ws_idx, wfrag, bias, out);
}

// Round 22
// 106.224 us; speedup vs baseline: 1.1633x; 1.0369x over previous
//
#include <hip/hip_runtime.h>
#include <hip/hip_bf16.h>
#include <stdint.h>
#include <float.h>

#define B_ 2
#define N_ 8192
#define C_ 64
#define K_ 16
#define D_IN 131     // 2C+3
#define XS_STRIDE 168
#define QPB 16       // queries per block (4 waves x 4 queries)
#define QPW 4        // queries per wave
#define CAP 128      // survivor buffer capacity per query

typedef __attribute__((ext_vector_type(8))) short short8v;
typedef __attribute__((ext_vector_type(4))) float f32x4;
typedef unsigned long long ull;

// sentinel: larger than any real key, but FINITE as f64 (NaN would break fmin/fmax)
#define SENT_U64 0x7F7FFFFFFFFFFFFFull

__device__ __forceinline__ float sq3(float x, float y, float z) {
#pragma clang fp contract(off)
  return (x * x + y * y) + z * z;
}

__device__ __forceinline__ uint64_t shfl_xor_u64(uint64_t x, int mask) {
  int lo = __shfl_xor((int)(uint32_t)(x & 0xffffffffull), mask, 64);
  int hi = __shfl_xor((int)(uint32_t)(x >> 32), mask, 64);
  return ((uint64_t)(uint32_t)hi << 32) | (uint32_t)lo;
}

__device__ __forceinline__ double shfl_xor_f64(double x, int mask) {
  return __builtin_bit_cast(double, shfl_xor_u64(__builtin_bit_cast(uint64_t, x), mask));
}

__device__ __forceinline__ uint64_t pack_key_u64(float d, int idx) {
  return ((uint64_t)__float_as_uint(d) << 32) | (uint32_t)idx;
}

// branchless sorted-insert: precondition key < hd[15]; 15-stage min/max ladder.
__device__ __forceinline__ void insert16(double* hd, double key) {
  hd[15] = key;
#pragma unroll
  for (int z = 15; z >= 1; --z) {
    double a = hd[z - 1], b = hd[z];
    hd[z - 1] = fmin(a, b);
    hd[z] = fmax(a, b);
  }
}

// exact reference distance (bit-identical to all passing rounds)
__device__ __forceinline__ float exact_d(float qx, float qy, float qz, float xxq,
                                         float4 cd) {
  float dot2 = fmaf(qz, cd.z, fmaf(qy, cd.y, qx * cd.x));
  float dtmp;
  {
#pragma clang fp contract(off)
    dtmp = (xxq + cd.w) - dot2;
  }
  return fmaxf(dtmp, 0.0f);
}

// ---- merged prep: W -> bf16 fragments, coords -> c4 = (2cx,2cy,2cz,|c|^2) ----
__global__ __launch_bounds__(256) void prep(const float* __restrict__ coords,
                                            const float* __restrict__ W,
                                            __hip_bfloat16* __restrict__ wfrag,
                                            float4* __restrict__ c4) {
  int i = blockIdx.x * 256 + threadIdx.x;
  if (i < 4 * 5 * 64 * 8) {
    int j = i & 7;
    int l = (i >> 3) & 63;
    int ks = (i >> 9) % 5;
    int nt = (i >> 9) / 5;
    int k = ks * 32 + (l >> 4) * 8 + j;
    int col = nt * 16 + (l & 15);
    float v = (k < D_IN) ? W[k * 64 + col] : 0.0f;
    wfrag[i] = __float2bfloat16(v);
  }
  int j2 = i - 4 * 5 * 64 * 8;
  if (j2 >= 0 && j2 < B_ * N_) {
    float cx = coords[j2 * 3 + 0], cy = coords[j2 * 3 + 1], cz = coords[j2 * 3 + 2];
    c4[j2] = make_float4(2.0f * cx, 2.0f * cy, 2.0f * cz, sq3(cx, cy, cz));
  }
}

// ---------------- KNN: global-direct scans, 8-deep ILP, idx-only push ----------------
__global__ __launch_bounds__(256) void knn_kernel(const float* __restrict__ coords,
                                                  const float4* __restrict__ c4,
                                                  int* __restrict__ idxout) {
  __shared__ int sbuf[QPB][CAP];
  __shared__ int scnt[QPB];
  const int t = threadIdx.x;
  const int w = t >> 6;                // wave 0..3
  const int lane = t & 63;
  const int blk = blockIdx.x;          // 1024 blocks: 512 per batch
  const int bb = blk >> 9;
  const int qbase = (blk & 511) * QPB;
  const float* cb = coords + (size_t)bb * N_ * 3;
  const float4* cg = c4 + (size_t)bb * N_;

  // this wave's 4 queries in registers (raw coords)
  float qx[QPW], qy[QPW], qz[QPW], xxq[QPW];
#pragma unroll
  for (int r = 0; r < QPW; ++r) {
    int n = qbase + w * QPW + r;
    qx[r] = cb[n * 3 + 0]; qy[r] = cb[n * 3 + 1]; qz[r] = cb[n * 3 + 2];
    xxq[r] = sq3(qx[r], qy[r], qz[r]);
  }
  if (t < QPB) scnt[t] = 0;
  __syncthreads();  // scnt visible before scan-2 pushes

// proxy = q.(2c) - w : 3 fma (the -w rides the innermost fma operand-negation)
#define PROXY(r, cd) fmaf(qz[r], (cd).z, fmaf(qy[r], (cd).y, fmaf(qx[r], (cd).x, -(cd).w)))

  // ---- scan 1 (global-direct, 8-deep ILP): per-lane running MAX proxy ----
  float M[QPW];
#pragma unroll
  for (int r = 0; r < QPW; ++r) M[r] = -FLT_MAX;

  for (int j0 = 0; j0 < N_; j0 += 512) {
    float4 c0 = cg[j0 + lane];
    float4 c1 = cg[j0 + 64 + lane];
    float4 c2 = cg[j0 + 128 + lane];
    float4 c3 = cg[j0 + 192 + lane];
    float4 c4v = cg[j0 + 256 + lane];
    float4 c5 = cg[j0 + 320 + lane];
    float4 c6 = cg[j0 + 384 + lane];
    float4 c7 = cg[j0 + 448 + lane];
#pragma unroll
    for (int r = 0; r < QPW; ++r) {
      float p0 = PROXY(r, c0);
      float p1 = PROXY(r, c1);
      float p2 = PROXY(r, c2);
      float p3 = PROXY(r, c3);
      float p4 = PROXY(r, c4v);
      float p5 = PROXY(r, c5);
      float p6 = PROXY(r, c6);
      float p7 = PROXY(r, c7);
      float m01 = fmaxf(p0, p1), m23 = fmaxf(p2, p3);
      float m45 = fmaxf(p4, p5), m67 = fmaxf(p6, p7);
      M[r] = fmaxf(M[r], fmaxf(fmaxf(m01, m23), fmaxf(m45, m67)));
    }
  }

  // ---- threshold: 16th LARGEST of the 64 lane-maxima per query ----
  float A[QPW], pT[QPW];
#pragma unroll
  for (int r = 0; r < QPW; ++r) { A[r] = M[r]; pT[r] = -FLT_MAX; }
#pragma unroll
  for (int rd = 0; rd < 16; ++rd) {
#pragma unroll
    for (int r = 0; r < QPW; ++r) {
      float g = A[r];
      g = fmaxf(g, __shfl_xor(g, 1, 64));
      g = fmaxf(g, __shfl_xor(g, 2, 64));
      g = fmaxf(g, __shfl_xor(g, 4, 64));
      g = fmaxf(g, __shfl_xor(g, 8, 64));
      g = fmaxf(g, __shfl_xor(g, 16, 64));
      g = fmaxf(g, __shfl_xor(g, 32, 64));
      pT[r] = g;
      A[r] = (A[r] == g) ? -FLT_MAX : A[r];
    }
  }
  // conservative proxy threshold X (few-ulp slop inflated ~25x): superset
  // collection is harmless since the final select uses exact keys.
  float X[QPW];
#pragma unroll
  for (int r = 0; r < QPW; ++r) {
    float slop = 6e-6f * (fabsf(xxq[r]) + fabsf(pT[r])) + 1e-5f;
    X[r] = fminf(pT[r], xxq[r]) - 2.0f * slop;
  }

  // ---- scan 2 (8-deep ILP): push INDEX only for survivors (proxy >= X) ----
  for (int j0 = 0; j0 < N_; j0 += 512) {
    const int ia = j0 + lane;
    float4 c0 = cg[ia];
    float4 c1 = cg[ia + 64];
    float4 c2 = cg[ia + 128];
    float4 c3 = cg[ia + 192];
    float4 c4v = cg[ia + 256];
    float4 c5 = cg[ia + 320];
    float4 c6 = cg[ia + 384];
    float4 c7 = cg[ia + 448];
#pragma unroll
    for (int r = 0; r < QPW; ++r) {
      float p0 = PROXY(r, c0);
      float p1 = PROXY(r, c1);
      float p2 = PROXY(r, c2);
      float p3 = PROXY(r, c3);
      float p4 = PROXY(r, c4v);
      float p5 = PROXY(r, c5);
      float p6 = PROXY(r, c6);
      float p7 = PROXY(r, c7);
      const int qr = w * QPW + r;
      if (p0 >= X[r]) { int pos = atomicAdd(&scnt[qr], 1); if (pos < CAP) sbuf[qr][pos] = ia; }
      if (p1 >= X[r]) { int pos = atomicAdd(&scnt[qr], 1); if (pos < CAP) sbuf[qr][pos] = ia + 64; }
      if (p2 >= X[r]) { int pos = atomicAdd(&scnt[qr], 1); if (pos < CAP) sbuf[qr][pos] = ia + 128; }
      if (p3 >= X[r]) { int pos = atomicAdd(&scnt[qr], 1); if (pos < CAP) sbuf[qr][pos] = ia + 192; }
      if (p4 >= X[r]) { int pos = atomicAdd(&scnt[qr], 1); if (pos < CAP) sbuf[qr][pos] = ia + 256; }
      if (p5 >= X[r]) { int pos = atomicAdd(&scnt[qr], 1); if (pos < CAP) sbuf[qr][pos] = ia + 320; }
      if (p6 >= X[r]) { int pos = atomicAdd(&scnt[qr], 1); if (pos < CAP) sbuf[qr][pos] = ia + 384; }
      if (p7 >= X[r]) { int pos = atomicAdd(&scnt[qr], 1); if (pos < CAP) sbuf[qr][pos] = ia + 448; }
    }
  }
  __syncthreads();

  // ---- exact select: 16 lanes per query; recompute exact-d per survivor ----
  const int qloc = t >> 4;             // 0..15: query within block
  const int s16 = t & 15;              // lane within 16-lane select group
  const int n = qbase + qloc;

  const float fqx = cb[n * 3 + 0], fqy = cb[n * 3 + 1], fqz = cb[n * 3 + 2];
  const float fxx = sq3(fqx, fqy, fqz);

  double hd[16];
#pragma unroll
  for (int i = 0; i < 16; ++i) hd[i] = __builtin_bit_cast(double, SENT_U64);

  const int cntv = scnt[qloc];
  if (cntv > CAP) {
    // overflow fallback (never expected): exact rescan from global, raw formula
    for (int j = s16; j < N_; j += 16) {
      float cx = cb[j * 3 + 0], cy = cb[j * 3 + 1], cz = cb[j * 3 + 2];
      float ww = sq3(cx, cy, cz);
      float dot = fmaf(fqz, cz, fmaf(fqy, cy, fqx * cx));
      float d2;
      {
#pragma clang fp contract(off)
        d2 = (fxx + ww) - 2.0f * dot;
      }
      d2 = fmaxf(d2, 0.0f);
      double k = __builtin_bit_cast(double, pack_key_u64(d2, j));
      if (k < hd[15]) insert16(hd, k);
    }
  } else {
    for (int i = s16; i < cntv; i += 16) {
      int idx = sbuf[qloc][i];
      float d = exact_d(fqx, fqy, fqz, fxx, cg[idx]);
      double k = __builtin_bit_cast(double, pack_key_u64(d, idx));
      if (k < hd[15]) insert16(hd, k);
    }
  }

  // merge the 16 per-lane sorted lists -> top-16 (ascending (dist,idx))
  int* myout = idxout + ((size_t)(bb * N_ + n)) * K_;
#pragma unroll
  for (int r = 0; r < 16; ++r) {
    double v = hd[0];
    v = fmin(v, shfl_xor_f64(v, 1));
    v = fmin(v, shfl_xor_f64(v, 2));
    v = fmin(v, shfl_xor_f64(v, 4));
    v = fmin(v, shfl_xor_f64(v, 8));
    if (__builtin_bit_cast(uint64_t, hd[0]) == __builtin_bit_cast(uint64_t, v)) {
#pragma unroll
      for (int z = 0; z < 15; ++z) hd[z] = hd[z + 1];
      hd[15] = __builtin_bit_cast(double, SENT_U64);
    }
    if (s16 == 0) myout[r] = (int)(uint32_t)__builtin_bit_cast(uint64_t, v);
  }
}

// ---------------- stage 2: gather + (16x131)@(131x64) + relu + max_k ----------------
__global__ __launch_bounds__(256) void stage2(const float* __restrict__ coords,
                                              const float* __restrict__ feat,
                                              const int* __restrict__ idxbuf,
                                              const __hip_bfloat16* __restrict__ wfrag,
                                              const float* __restrict__ bias,
                                              float* __restrict__ out) {
  __shared__ __align__(16) __hip_bfloat16 xs[4][16][XS_STRIDE];
  const int t = threadIdx.x;
  const int w = t >> 6;
  const int lane = t & 63;
  const int q = blockIdx.x * 4 + w;
  const int bb = q >> 13;
  const int n = q & (N_ - 1);
  const float* cb = coords + (size_t)bb * N_ * 3;
  const float* fb = feat + (size_t)bb * N_ * C_;
  const int* myidx = idxbuf + (size_t)q * K_;

  float fi = fb[(size_t)n * C_ + lane];
  float qc = (lane < 3) ? cb[n * 3 + lane] : 0.0f;

#pragma unroll
  for (int k = 0; k < K_; ++k) {
    int nb = myidx[k];
    float nf = fb[(size_t)nb * C_ + lane];
    xs[w][k][lane] = __float2bfloat16(fi);
    xs[w][k][C_ + lane] = __float2bfloat16(nf - fi);
    if (lane < 3) {
      xs[w][k][128 + lane] = __float2bfloat16(cb[nb * 3 + lane] - qc);
    } else if (lane < 40) {
      xs[w][k][128 + lane] = __float2bfloat16(0.0f);  // zero-pad d = 131..167
    }
  }
  __syncthreads();

  const int row = lane & 15;   // = output channel within 16-col tile (D's col)
  const int g = lane >> 4;
  short8v a[5];
#pragma unroll
  for (int ks = 0; ks < 5; ++ks)
    a[ks] = *(const short8v*)&xs[w][row][ks * 32 + g * 8];

  const short8v* wf = (const short8v*)wfrag;
#pragma unroll
  for (int nt = 0; nt < 4; ++nt) {
    f32x4 acc = {0.f, 0.f, 0.f, 0.f};
#pragma unroll
    for (int ks = 0; ks < 5; ++ks) {
      short8v bf = wf[(nt * 5 + ks) * 64 + lane];
      acc = __builtin_amdgcn_mfma_f32_16x16x32_bf16(a[ks], bf, acc, 0, 0, 0);
    }
    float bcol = bias[nt * 16 + row];
    float m = fmaxf(fmaxf(fmaxf(acc[0] + bcol, 0.f), fmaxf(acc[1] + bcol, 0.f)),
                    fmaxf(fmaxf(acc[2] + bcol, 0.f), fmaxf(acc[3] + bcol, 0.f)));
    m = fmaxf(m, __shfl_xor(m, 16, 64));
    m = fmaxf(m, __shfl_xor(m, 32, 64));
    if (lane < 16) out[(size_t)q * C_ + nt * 16 + row] = m;
  }
}

extern "C" void kernel_launch(void* const* d_in, const int* in_sizes, int n_in,
                              void* d_out, int out_size, void* d_ws, size_t ws_size,
                              hipStream_t stream) {
  const float* coords = (const float*)d_in[0];
  const float* feat = (const float*)d_in[1];
  const float* W = (const float*)d_in[2];
  const float* bias = (const float*)d_in[3];
  float* out = (float*)d_out;

  int* ws_idx = (int*)d_ws;                                   // B*N*K ints = 1 MiB
  char* p = (char*)d_ws + (size_t)B_ * N_ * K_ * sizeof(int);
  __hip_bfloat16* wfrag = (__hip_bfloat16*)p;                 // 20 KiB
  float4* c4 = (float4*)(p + 32768);                          // 256 KiB, 16B-aligned

  const int prep_elems = 4 * 5 * 64 * 8 + B_ * N_;
  prep<<<(prep_elems + 255) / 256, 256, 0, stream>>>(coords, W, wfrag, c4);
  knn_kernel<<<(B_ * N_) / QPB, 256, 0, stream>>>(coords, c4, ws_idx);
  stage2<<<(B_ * N_) / 4, 256, 0, stream>>>(coords, feat, ws_idx, wfrag, bias, out);
}